// Round 1
// baseline (1784.041 us; speedup 1.0000x reference)
//
#include <hip/hip_runtime.h>
#include <stddef.h>

// Llama4 experts MoE MLP: E=8, tokens/expert=1024, H=2048, I=4096.
// GEMM1 (x @ Wgu) + SwiGLU -> act(bf16, in d_ws, 64MB)   [needs ws_size >= 64MB]
// GEMM2 (act @ Wd) -> out(fp32)
// bf16 MFMA 16x16x32, fp32 accumulate; fp32->bf16 RNE conversion in staging.

#define NEXP 8
#define TPE  1024
#define HDIM 2048
#define IDIM 4096
#define NN2  (2 * IDIM)   // 8192

typedef __bf16 bf16x8 __attribute__((ext_vector_type(8)));
typedef float  f32x4  __attribute__((ext_vector_type(4)));
typedef unsigned short u16x8 __attribute__((ext_vector_type(8)));

static __device__ __forceinline__ unsigned short f2bf(float f) {
  unsigned u = __builtin_bit_cast(unsigned, f);
  u += 0x7FFFu + ((u >> 16) & 1u);           // round-to-nearest-even
  return (unsigned short)(u >> 16);
}

static __device__ __forceinline__ bf16x8 frag_ld(const unsigned short* p) {
  u16x8 v = *(const u16x8*)p;
  return __builtin_bit_cast(bf16x8, v);
}

// ---------------------------------------------------------------------------
// GEMM1 + SwiGLU. Tile: 128 tokens x (64 gate cols + 64 up cols), BK=32.
// grid = 8 experts * 8 mb * 64 nb = 4096 blocks, 256 threads (4 waves 2x2).
// ---------------------------------------------------------------------------
#define G1_NK (HDIM / 32)   // 64 K-iterations

__global__ __launch_bounds__(256, 2) void k_gemm1_swiglu(
    const float* __restrict__ hs, const float* __restrict__ wgu,
    unsigned short* __restrict__ act)
{
  __shared__ unsigned short sA [2][128][40];  // [row][k], pad to 40 (80B rows)
  __shared__ unsigned short sBg[2][64][40];   // [col][k] (transposed gate tile)
  __shared__ unsigned short sBu[2][64][40];   // [col][k] (transposed up tile)

  const int t  = threadIdx.x;
  const int bx = blockIdx.x;
  const int mb = bx & 7;            // mb fastest: 8 consecutive blocks share B panel
  const int nb = (bx >> 3) & 63;
  const int e  = bx >> 9;

  const float* A  = hs  + (size_t)(e * TPE + mb * 128) * HDIM;
  const float* Bg = wgu + (size_t)e * HDIM * NN2 + nb * 64;
  const float* Bu = Bg + IDIM;
  unsigned short* actp = act + (size_t)e * TPE * IDIM + (size_t)(mb * 128) * IDIM + nb * 64;

  // staging roles
  const int ar  = t >> 1;            // A row 0..127
  const int ak  = (t & 1) << 4;      // A k-offset 0/16 (16 floats each)
  const int bn  = t & 63;            // B col within tile
  const int bk8 = (t >> 6) << 3;     // B k-group 0,8,16,24

  // compute roles
  const int lane = t & 63;
  const int wave = t >> 6;
  const int wr = (wave >> 1) * 64;   // wave row base
  const int wc = (wave & 1) * 32;    // wave col base (paired tile is 64 wide)
  const int fr = lane & 15;
  const int fk = (lane >> 4) << 3;   // 0,8,16,24

  f32x4 accg[4][2], accu[4][2];
#pragma unroll
  for (int m = 0; m < 4; ++m)
#pragma unroll
    for (int n = 0; n < 2; ++n) { accg[m][n] = (f32x4)0.0f; accu[m][n] = (f32x4)0.0f; }

  auto stage = [&](int b, int k0) {
    // A: 16 contiguous floats -> 16 bf16, two b128 LDS writes
    const f32x4* ap = (const f32x4*)(A + (size_t)ar * HDIM + k0 + ak);
    f32x4 v0 = ap[0], v1 = ap[1], v2 = ap[2], v3 = ap[3];
    u16x8 lo, hi;
#pragma unroll
    for (int j = 0; j < 4; ++j) {
      lo[j] = f2bf(v0[j]); lo[4 + j] = f2bf(v1[j]);
      hi[j] = f2bf(v2[j]); hi[4 + j] = f2bf(v3[j]);
    }
    *(u16x8*)&sA[b][ar][ak]     = lo;
    *(u16x8*)&sA[b][ar][ak + 8] = hi;
    // B gate: gather 8 k for one col (coalesced across lanes), transpose into [n][k]
    const float* gp = Bg + (size_t)(k0 + bk8) * NN2 + bn;
    u16x8 pg;
#pragma unroll
    for (int j = 0; j < 8; ++j) pg[j] = f2bf(gp[(size_t)j * NN2]);
    *(u16x8*)&sBg[b][bn][bk8] = pg;
    // B up
    const float* up = Bu + (size_t)(k0 + bk8) * NN2 + bn;
    u16x8 pu;
#pragma unroll
    for (int j = 0; j < 8; ++j) pu[j] = f2bf(up[(size_t)j * NN2]);
    *(u16x8*)&sBu[b][bn][bk8] = pu;
  };

  auto compute = [&](int b) {
    bf16x8 af[4], bg[2], bu[2];
#pragma unroll
    for (int m = 0; m < 4; ++m) af[m] = frag_ld(&sA[b][wr + m * 16 + fr][fk]);
#pragma unroll
    for (int n = 0; n < 2; ++n) bg[n] = frag_ld(&sBg[b][wc + n * 16 + fr][fk]);
#pragma unroll
    for (int n = 0; n < 2; ++n) bu[n] = frag_ld(&sBu[b][wc + n * 16 + fr][fk]);
#pragma unroll
    for (int m = 0; m < 4; ++m)
#pragma unroll
      for (int n = 0; n < 2; ++n) {
        accg[m][n] = __builtin_amdgcn_mfma_f32_16x16x32_bf16(af[m], bg[n], accg[m][n], 0, 0, 0);
        accu[m][n] = __builtin_amdgcn_mfma_f32_16x16x32_bf16(af[m], bu[n], accu[m][n], 0, 0, 0);
      }
  };

  stage(0, 0);
  for (int kt = 0; kt < G1_NK; kt += 2) {
    __syncthreads();
    stage(1, (kt + 1) * 32);
    compute(0);
    __syncthreads();
    if (kt + 2 < G1_NK) stage(0, (kt + 2) * 32);
    compute(1);
  }

  // SwiGLU epilogue: act = up * gate * sigmoid(gate), store bf16
#pragma unroll
  for (int m = 0; m < 4; ++m) {
#pragma unroll
    for (int n = 0; n < 2; ++n) {
      const int row0 = wr + m * 16 + ((lane >> 4) << 2);
      const int col  = wc + n * 16 + fr;
#pragma unroll
      for (int j = 0; j < 4; ++j) {
        float g = accg[m][n][j];
        float u = accu[m][n][j];
        float s = u * g / (1.0f + __expf(-g));
        actp[(size_t)(row0 + j) * IDIM + col] = f2bf(s);
      }
    }
  }
}

// ---------------------------------------------------------------------------
// GEMM2: out = act @ down. Tile 128x128, BK=32.
// grid = 8 experts * 8 mb * 16 nb = 1024 blocks, 256 threads (4 waves 2x2).
// ---------------------------------------------------------------------------
#define G2_NK (IDIM / 32)   // 128 K-iterations

__global__ __launch_bounds__(256, 2) void k_gemm2(
    const unsigned short* __restrict__ act, const float* __restrict__ wd,
    float* __restrict__ out)
{
  __shared__ unsigned short sA[2][128][40];
  __shared__ unsigned short sB[2][128][40];

  const int t  = threadIdx.x;
  const int bx = blockIdx.x;
  const int mb = bx & 7;
  const int nb = (bx >> 3) & 15;
  const int e  = bx >> 7;

  const unsigned short* A = act + (size_t)e * TPE * IDIM + (size_t)(mb * 128) * IDIM;
  const float* B = wd + (size_t)e * IDIM * HDIM + nb * 128;
  float* Cp = out + (size_t)(e * TPE + mb * 128) * HDIM + nb * 128;

  const int ar  = t >> 1;            // A row
  const int ah  = (t & 1) << 4;      // A k-offset 0/16 (16 bf16 = 32B)
  const int bn  = t & 127;           // B col
  const int bk8 = (t >> 7) << 3;     // 0 or 8

  const int lane = t & 63;
  const int wave = t >> 6;
  const int wr = (wave >> 1) * 64;
  const int wc = (wave & 1) * 64;
  const int fr = lane & 15;
  const int fk = (lane >> 4) << 3;

  f32x4 acc[4][4];
#pragma unroll
  for (int m = 0; m < 4; ++m)
#pragma unroll
    for (int n = 0; n < 4; ++n) acc[m][n] = (f32x4)0.0f;

  auto stage = [&](int b, int k0) {
    // A: bf16 already, two 16B copies
    const u16x8* ap = (const u16x8*)(A + (size_t)ar * IDIM + k0 + ah);
    u16x8 a0 = ap[0], a1 = ap[1];
    *(u16x8*)&sA[b][ar][ah]     = a0;
    *(u16x8*)&sA[b][ar][ah + 8] = a1;
    // B: two gathers of 8 k, transpose+convert
    const float* bp = B + (size_t)(k0 + bk8) * HDIM + bn;
    u16x8 p0, p1;
#pragma unroll
    for (int j = 0; j < 8; ++j) p0[j] = f2bf(bp[(size_t)j * HDIM]);
    const float* bp2 = bp + (size_t)16 * HDIM;
#pragma unroll
    for (int j = 0; j < 8; ++j) p1[j] = f2bf(bp2[(size_t)j * HDIM]);
    *(u16x8*)&sB[b][bn][bk8]      = p0;
    *(u16x8*)&sB[b][bn][bk8 + 16] = p1;
  };

  auto compute = [&](int b) {
    bf16x8 af[4], bf[4];
#pragma unroll
    for (int m = 0; m < 4; ++m) af[m] = frag_ld(&sA[b][wr + m * 16 + fr][fk]);
#pragma unroll
    for (int n = 0; n < 4; ++n) bf[n] = frag_ld(&sB[b][wc + n * 16 + fr][fk]);
#pragma unroll
    for (int m = 0; m < 4; ++m)
#pragma unroll
      for (int n = 0; n < 4; ++n)
        acc[m][n] = __builtin_amdgcn_mfma_f32_16x16x32_bf16(af[m], bf[n], acc[m][n], 0, 0, 0);
  };

  stage(0, 0);
  for (int kt = 0; kt < G2_NK; kt += 2) {
    __syncthreads();
    stage(1, (kt + 1) * 32);
    compute(0);
    __syncthreads();
    if (kt + 2 < G2_NK) stage(0, (kt + 2) * 32);
    compute(1);
  }

#pragma unroll
  for (int m = 0; m < 4; ++m) {
#pragma unroll
    for (int n = 0; n < 4; ++n) {
      const int row0 = wr + m * 16 + ((lane >> 4) << 2);
      const int col  = wc + n * 16 + fr;
#pragma unroll
      for (int j = 0; j < 4; ++j)
        Cp[(size_t)(row0 + j) * HDIM + col] = acc[m][n][j];
    }
  }
}

extern "C" void kernel_launch(void* const* d_in, const int* in_sizes, int n_in,
                              void* d_out, int out_size, void* d_ws, size_t ws_size,
                              hipStream_t stream) {
  const float* hs  = (const float*)d_in[0];   // [8192, 2048]
  const float* wgu = (const float*)d_in[1];   // [8, 2048, 8192]
  const float* wd  = (const float*)d_in[2];   // [8, 4096, 2048]
  float* out = (float*)d_out;                 // [8192, 2048] fp32
  unsigned short* act = (unsigned short*)d_ws; // bf16 [8, 1024, 4096] = 64MB

  k_gemm1_swiglu<<<4096, 256, 0, stream>>>(hs, wgu, act);
  k_gemm2<<<1024, 256, 0, stream>>>(act, wd, out);
}